// Round 5
// baseline (308.050 us; speedup 1.0000x reference)
//
#include <hip/hip_runtime.h>
#include <stdint.h>

typedef _Float16 f16;
typedef __attribute__((ext_vector_type(8)))  _Float16 f16x8;
typedef __attribute__((ext_vector_type(4)))  float    f32x4;

#define NSTEPS 79
#define CDIM   256
#define ROWS   16
#define NKS    8              // h k-steps (8 x K=32)
#define AUGKS  8              // augmented k-step carrying x
#define PLANE  9216           // bytes per plane: 9 ksteps * 64 chunks * 16B
#define BUFSZ  (2*PLANE)      // one h buffer = hi plane + lo plane

#define SGB(mask, n) __builtin_amdgcn_sched_group_barrier((mask), (n), 0)
// masks: 0x8 = MFMA, 0x100 = DS_READ

// ---------------------------------------------------------------------------
// h storage: DOUBLE-BUFFERED, each buffer = two f16 planes, FRAGMENT-MAJOR:
//   hi-plane: f16(h);  lo-plane: f16(h - hi)  (unscaled -> same B operand,
//   single accumulator: acc += a_hi*B + a_lo*B)
//   kstep ks, chunk dl (0..63), elem i (0..7):
//     holds A[m = dl&15][k = ks*32 + (dl>>4)*8 + i]
//   byte = ks*1024 + swz(dl,ks)*16 + i*2,  swz = dl ^ ((dl>>3)&7) ^ (ks&7)
// kstep 8 = augmented x tile, ONE B operand Baug = [Wx_hi(r0-3); Wx_lo(r4-7)]:
//   hi-plane aug A = [x_hi | x_hi]  -> x_hi*Wx_hi + x_hi*Wx_lo
//   lo-plane aug A = [x_lo | 0   ]  -> x_lo*Wx_hi            (no lo*lo term)
// Step t: reads buf[t&1], writes h(t+1)+x(t+1) into buf[(t+1)&1], ONE barrier.
// sched_group_barrier (DS_READ 2, MFMA 4) x9 caps ds_read prefetch depth so
// transient pressure stays under the 128-VGPR cap (R3/R4's 170MB scratch
// traffic came from scheduler-hoisted fragment loads spilling ~2 dw/thread/it)
// ---------------------------------------------------------------------------

__device__ __forceinline__ uint32_t pack_hl(float v) {
    f16 hi = (f16)v;
    f16 lo = (f16)(v - (float)hi);
    return (uint32_t)__builtin_bit_cast(unsigned short, hi)
         | ((uint32_t)__builtin_bit_cast(unsigned short, lo) << 16);
}

// MFMA 16x16x32_f16 layout (verified R1):
//   A: lane l holds A[m = l&15][k = 8*(l>>4)+i]
//   B: lane l holds B[k = 8*(l>>4)+i][n = l&15]
//   C/D: lane l, reg r -> C[row = (l>>4)*4 + r][col = l&15]

__global__ __launch_bounds__(512, 4) void rnn_fused(
    const float* __restrict__ x0p, const float* __restrict__ x1p,
    const float* __restrict__ x2p, const float* __restrict__ x3p,
    const float* __restrict__ Wx,  const float* __restrict__ Wh,
    const float* __restrict__ brnn,const float* __restrict__ Wd,
    const float* __restrict__ bd,  float* __restrict__ out)
{
    __shared__ __align__(16) char     hpl[2*BUFSZ];          // 36864 B
    __shared__ __align__(16) uint32_t xs[ROWS][NSTEPS][4];   // 20224 B packed hi|lo, reversed

    const int tid  = (int)threadIdx.x;
    const int w    = tid >> 6;        // wave 0..7 -> cols [w*32, w*32+32)
    const int l    = tid & 63;
    const int ln16 = l & 15;
    const int kgl  = l >> 4;          // 0..3
    const int r0   = (int)blockIdx.x * ROWS;
    const int n0   = w * 32;

    char* hb = hpl;

    // -------- Wh-hi fragments + single augmented Wx fragment --------
    f16x8 B1[2][NKS];          // reused for Wd after the recurrence
    f16x8 Baug[2];
    #pragma unroll
    for (int nt = 0; nt < 2; ++nt) {
        const int n = n0 + nt*16 + ln16;
        #pragma unroll
        for (int ks = 0; ks < NKS; ++ks) {
            const int k0 = ks*32 + kgl*8;
            f16x8 b;
            #pragma unroll
            for (int i = 0; i < 8; ++i)
                b[i] = (f16)Wh[(size_t)(k0 + i)*CDIM + n];
            B1[nt][ks] = b;
        }
        f16x8 e;
        #pragma unroll
        for (int i = 0; i < 8; ++i) e[i] = (f16)0.0f;
        if (kgl == 0) {
            #pragma unroll
            for (int i = 0; i < 4; ++i) {
                float wv = Wx[i*CDIM + n];
                f16 whi = (f16)wv;
                e[i]   = whi;                       // rows 0-3: Wx_hi (vs x_hi / x_lo)
                e[i+4] = (f16)(wv - (float)whi);    // rows 4-7: Wx_lo (vs x_hi dup)
            }
        }
        Baug[nt] = e;
    }
    const float bias0 = brnn[n0 + ln16];
    const float bias1 = brnn[n0 + 16 + ln16];

    // -------- precomputed LDS addresses (relative to a buffer base) --------
    const unsigned rba = (unsigned)((l ^ ((l >> 3) & 7)) * 16);
    int waddr[2][4];
    #pragma unroll
    for (int nt = 0; nt < 2; ++nt) {
        const int kgroup = 2*nt + (ln16 >> 3);
        const int i      = ln16 & 7;
        #pragma unroll
        for (int r = 0; r < 4; ++r) {
            const int mr = kgl*4 + r;
            const int dl = mr + 16*kgroup;
            const int sw = dl ^ ((dl >> 3) & 7) ^ (w & 7);
            waddr[nt][r] = w*1024 + sw*16 + i*2;
        }
    }
    // x-writer (wave 0 lanes): m = ln16, f = kgl
    const int xm     = ln16;
    const int xf4    = kgl;
    const int xswz   = xm ^ ((xm >> 3) & 7);     // ks=8 -> ks&7=0
    const int xaddr  = AUGKS*1024 + xswz*16 + xf4*2;
    const int xsbase = xm*NSTEPS*4 + xf4;        // word offset, + t*4 per step

    // -------- init: zero both buffers, stage x (packed, time-reversed) ------
    for (int i = tid; i < (2*BUFSZ)/4; i += 512)
        ((uint32_t*)hb)[i] = 0u;
    {
        const float* xfp[4] = {x0p, x1p, x2p, x3p};
        #pragma unroll
        for (int f = 0; f < 4; ++f) {
            const float* xf = xfp[f];
            for (int idx = tid; idx < ROWS*NSTEPS; idx += 512) {
                int m  = idx / NSTEPS;
                int lt = idx - m*NSTEPS;
                xs[m][(NSTEPS-1) - lt][f] = pack_hl(xf[(size_t)(r0 + m)*NSTEPS + lt]);
            }
        }
    }
    __syncthreads();
    // x tile for t=0 into buffer 0
    if (tid < 64) {
        uint32_t u = (&xs[0][0][0])[xsbase];
        unsigned short hi = (unsigned short)(u & 0xFFFFu);
        unsigned short lo = (unsigned short)(u >> 16);
        *(unsigned short*)(hb + xaddr)         = hi;   // hi-plane k'=f    (x_hi)
        *(unsigned short*)(hb + xaddr + 8)     = hi;   // hi-plane k'=4+f  (x_hi dup)
        *(unsigned short*)(hb + xaddr + PLANE) = lo;   // lo-plane k'=f    (x_lo)
    }
    __syncthreads();

    // -------- recurrence: ONE barrier per step --------
    #pragma unroll 1
    for (int t = 0; t < NSTEPS; ++t) {
        const char* cbuf = hb + (t & 1)*BUFSZ;
        char*       nbuf = hb + ((t + 1) & 1)*BUFSZ;

        f32x4 acc0 = {bias0, bias0, bias0, bias0};
        f32x4 acc1 = {bias1, bias1, bias1, bias1};

        #pragma unroll
        for (int ks = 0; ks < NKS; ++ks) {
            const unsigned ra = (unsigned)(ks*1024) + (rba ^ (unsigned)((ks & 7) << 4));
            f16x8 a1 = *(const f16x8*)(cbuf + ra);
            f16x8 a2 = *(const f16x8*)(cbuf + PLANE + ra);
            acc0 = __builtin_amdgcn_mfma_f32_16x16x32_f16(a1, B1[0][ks], acc0, 0, 0, 0);
            acc1 = __builtin_amdgcn_mfma_f32_16x16x32_f16(a1, B1[1][ks], acc1, 0, 0, 0);
            acc0 = __builtin_amdgcn_mfma_f32_16x16x32_f16(a2, B1[0][ks], acc0, 0, 0, 0);
            acc1 = __builtin_amdgcn_mfma_f32_16x16x32_f16(a2, B1[1][ks], acc1, 0, 0, 0);
            SGB(0x100, 2);   // 2 ds_read_b128
            SGB(0x8,   4);   // 4 mfma
        }
        {   // augmented x k-step
            const unsigned ra = (unsigned)(AUGKS*1024) + rba;
            f16x8 a1 = *(const f16x8*)(cbuf + ra);
            f16x8 a2 = *(const f16x8*)(cbuf + PLANE + ra);
            acc0 = __builtin_amdgcn_mfma_f32_16x16x32_f16(a1, Baug[0], acc0, 0, 0, 0);
            acc1 = __builtin_amdgcn_mfma_f32_16x16x32_f16(a1, Baug[1], acc1, 0, 0, 0);
            acc0 = __builtin_amdgcn_mfma_f32_16x16x32_f16(a2, Baug[0], acc0, 0, 0, 0);
            acc1 = __builtin_amdgcn_mfma_f32_16x16x32_f16(a2, Baug[1], acc1, 0, 0, 0);
            SGB(0x100, 2);
            SGB(0x8,   4);
        }

        // next step's x tile -> other buffer (no hazard: nobody reads nbuf yet)
        if (tid < 64 && t + 1 < NSTEPS) {
            uint32_t u = (&xs[0][0][0])[xsbase + (t + 1)*4];
            unsigned short hi = (unsigned short)(u & 0xFFFFu);
            unsigned short lo = (unsigned short)(u >> 16);
            *(unsigned short*)(nbuf + xaddr)         = hi;
            *(unsigned short*)(nbuf + xaddr + 8)     = hi;
            *(unsigned short*)(nbuf + xaddr + PLANE) = lo;
        }
        // h(t+1): relu, split hi/lo, store both planes into other buffer
        #pragma unroll
        for (int r = 0; r < 4; ++r) {
            float v0 = acc0[r];
            v0 = v0 > 0.f ? v0 : 0.f;
            f16 h0 = (f16)v0;
            f16 l0 = (f16)(v0 - (float)h0);
            *(f16*)(nbuf + waddr[0][r])         = h0;
            *(f16*)(nbuf + waddr[0][r] + PLANE) = l0;
            float v1 = acc1[r];
            v1 = v1 > 0.f ? v1 : 0.f;
            f16 h1 = (f16)v1;
            f16 l1 = (f16)(v1 - (float)h1);
            *(f16*)(nbuf + waddr[1][r])         = h1;
            *(f16*)(nbuf + waddr[1][r] + PLANE) = l1;
        }
        __syncthreads();   // h(t+1)/x(t+1) visible; cbuf free to overwrite next step
    }

    // -------- final dense: out = relu(h @ Wd + b_d), reuse B1 regs --------
    // NSTEPS odd -> final h is in buffer 1
    #pragma unroll
    for (int nt = 0; nt < 2; ++nt) {
        const int n = n0 + nt*16 + ln16;
        #pragma unroll
        for (int ks = 0; ks < NKS; ++ks) {
            const int k0 = ks*32 + kgl*8;
            f16x8 b;
            #pragma unroll
            for (int i = 0; i < 8; ++i)
                b[i] = (f16)Wd[(size_t)(k0 + i)*CDIM + n];
            B1[nt][ks] = b;
        }
    }
    {
        const char* rp = hb + BUFSZ;
        const float bd0 = bd[n0 + ln16];
        const float bd1 = bd[n0 + 16 + ln16];
        f32x4 acc0 = {bd0, bd0, bd0, bd0};
        f32x4 acc1 = {bd1, bd1, bd1, bd1};
        #pragma unroll
        for (int ks = 0; ks < NKS; ++ks) {
            const unsigned ra = (unsigned)(ks*1024) + (rba ^ (unsigned)((ks & 7) << 4));
            f16x8 a1 = *(const f16x8*)(rp + ra);
            f16x8 a2 = *(const f16x8*)(rp + PLANE + ra);
            acc0 = __builtin_amdgcn_mfma_f32_16x16x32_f16(a1, B1[0][ks], acc0, 0, 0, 0);
            acc1 = __builtin_amdgcn_mfma_f32_16x16x32_f16(a1, B1[1][ks], acc1, 0, 0, 0);
            acc0 = __builtin_amdgcn_mfma_f32_16x16x32_f16(a2, B1[0][ks], acc0, 0, 0, 0);
            acc1 = __builtin_amdgcn_mfma_f32_16x16x32_f16(a2, B1[1][ks], acc1, 0, 0, 0);
        }
        #pragma unroll
        for (int r = 0; r < 4; ++r) {
            const int mr = kgl*4 + r;
            float v0 = acc0[r];
            v0 = v0 > 0.f ? v0 : 0.f;
            out[(size_t)(r0 + mr)*CDIM + (n0 + ln16)] = v0;
            float v1 = acc1[r];
            v1 = v1 > 0.f ? v1 : 0.f;
            out[(size_t)(r0 + mr)*CDIM + (n0 + 16 + ln16)] = v1;
        }
    }
}

extern "C" void kernel_launch(void* const* d_in, const int* in_sizes, int n_in,
                              void* d_out, int out_size, void* d_ws, size_t ws_size,
                              hipStream_t stream)
{
    (void)in_sizes; (void)n_in; (void)out_size; (void)d_ws; (void)ws_size;
    const float* x0 = (const float*)d_in[0];
    const float* x1 = (const float*)d_in[1];
    const float* x2 = (const float*)d_in[2];
    const float* x3 = (const float*)d_in[3];
    const float* Wx = (const float*)d_in[4];
    const float* Wh = (const float*)d_in[5];
    const float* br = (const float*)d_in[6];
    const float* Wd = (const float*)d_in[7];
    const float* bd = (const float*)d_in[8];
    float* out = (float*)d_out;

    rnn_fused<<<dim3(8192 / ROWS), dim3(512), 0, stream>>>(
        x0, x1, x2, x3, Wx, Wh, br, Wd, bd, out);
}

// Round 6
// 245.826 us; speedup vs baseline: 1.2531x; 1.2531x over previous
//
#include <hip/hip_runtime.h>
#include <stdint.h>

typedef _Float16 f16;
typedef __attribute__((ext_vector_type(8)))  _Float16 f16x8;
typedef __attribute__((ext_vector_type(4)))  float    f32x4;

#define NSTEPS 79
#define CDIM   256
#define ROWS   32
#define NKS    8                 // h k-steps (8 x K=32)
#define MTSZ   (9*1024)          // bytes per m-tile per plane (9 ksteps)
#define PLANE  (2*MTSZ)          // bytes per plane (2 m-tiles)
#define BUFSZ  (2*PLANE)         // 36864 B total: 2 planes (hi, lo)

// ---------------------------------------------------------------------------
// Single h buffer, two f16 planes (hi = f16(h), lo = f16(h-hi)), FRAGMENT-
// MAJOR per m-tile:
//   offset(plane,mt,ks,dl,i) = plane*PLANE + mt*MTSZ + ks*1024 + swz(dl,ks)*16 + i*2
//   chunk dl holds A[m = dl&15][k = ks*32 + (dl>>4)*8 + i],
//   swz(dl,ks) = dl ^ ((dl>>3)&7) ^ (ks&7)   (bijective, conflict-free b128 reads)
// kstep 8 = augmented x tile, B operand Baug = [Wx_hi(r0-3); Wx_lo(r4-7)]:
//   hi-plane aug A = [x_hi | x_hi]  -> x_hi*Wx_hi + x_hi*Wx_lo
//   lo-plane aug A = [x_lo | 0   ]  -> x_lo*Wx_hi        (no lo*lo term)
// x is NOT staged in LDS: prefetched from global each step (latency hidden
// under the MFMA phase), written into the aug tile after barrier 1.
//
// R3-R5 lesson: __launch_bounds__(512,4)'s 128-reg cap made the allocator
// demote B1[2][8] to scratch (VGPR_Count=64, 183MB scratch WRITE traffic).
// (512,2) -> 256-reg cap; demand ~120 -> everything stays in registers.
// ---------------------------------------------------------------------------

// MFMA 16x16x32_f16 layout (verified R1):
//   A: lane l holds A[m = l&15][k = 8*(l>>4)+i]
//   B: lane l holds B[k = 8*(l>>4)+i][n = l&15]
//   C/D: lane l, reg r -> C[row = (l>>4)*4 + r][col = l&15]

__global__ __launch_bounds__(512, 2) void rnn_fused(
    const float* __restrict__ x0p, const float* __restrict__ x1p,
    const float* __restrict__ x2p, const float* __restrict__ x3p,
    const float* __restrict__ Wx,  const float* __restrict__ Wh,
    const float* __restrict__ brnn,const float* __restrict__ Wd,
    const float* __restrict__ bd,  float* __restrict__ out)
{
    __shared__ __align__(16) char hb[BUFSZ];   // 36864 B

    const int tid  = (int)threadIdx.x;
    const int w    = tid >> 6;        // wave 0..7 -> cols [w*32, w*32+32)
    const int l    = tid & 63;
    const int ln16 = l & 15;
    const int kgl  = l >> 4;          // 0..3
    const int r0   = (int)blockIdx.x * ROWS;
    const int n0   = w * 32;

    // -------- Wh-hi fragments + single augmented Wx fragment --------
    f16x8 B1[2][NKS];          // reused for Wd after the recurrence
    f16x8 Baug[2];
    #pragma unroll
    for (int nt = 0; nt < 2; ++nt) {
        const int n = n0 + nt*16 + ln16;
        #pragma unroll
        for (int ks = 0; ks < NKS; ++ks) {
            const int k0 = ks*32 + kgl*8;
            f16x8 b;
            #pragma unroll
            for (int i = 0; i < 8; ++i)
                b[i] = (f16)Wh[(size_t)(k0 + i)*CDIM + n];
            B1[nt][ks] = b;
        }
        f16x8 e;
        #pragma unroll
        for (int i = 0; i < 8; ++i) e[i] = (f16)0.0f;
        if (kgl == 0) {
            #pragma unroll
            for (int i = 0; i < 4; ++i) {
                float wv = Wx[i*CDIM + n];
                f16 whi = (f16)wv;
                e[i]   = whi;                       // rows 0-3: Wx_hi
                e[i+4] = (f16)(wv - (float)whi);    // rows 4-7: Wx_lo
            }
        }
        Baug[nt] = e;
    }
    const float bias0 = brnn[n0 + ln16];
    const float bias1 = brnn[n0 + 16 + ln16];

    // -------- precomputed LDS addresses --------
    const unsigned rba = (unsigned)((l ^ ((l >> 3) & 7)) * 16);   // read base
    int waddr[2][4];   // h-write address (within plane 0, mt 0); + mt*MTSZ, + PLANE
    #pragma unroll
    for (int nt = 0; nt < 2; ++nt) {
        const int kgroup = 2*nt + (ln16 >> 3);
        const int i      = ln16 & 7;
        #pragma unroll
        for (int r = 0; r < 4; ++r) {
            const int mr = kgl*4 + r;
            const int dl = mr + 16*kgroup;
            const int sw = dl ^ ((dl >> 3) & 7) ^ (w & 7);
            waddr[nt][r] = w*1024 + sw*16 + i*2;
        }
    }
    // x writer: lanes tid<128 -> (row m_full = tid>>2, feature f = tid&3)
    const int  mfull = tid >> 2;
    const int  xf    = tid & 3;
    const int  xmt   = mfull >> 4;
    const int  xm    = mfull & 15;
    const int  xbase = xmt*MTSZ + NKS*1024 + (xm ^ ((xm >> 3) & 7))*16;
    const float* xptr = (xf == 0) ? x0p : (xf == 1) ? x1p : (xf == 2) ? x2p : x3p;
    const bool xwriter = (tid < 128);

    // -------- init: zero buffer; write aug(0) --------
    for (int i = tid; i < BUFSZ/4; i += 512)
        ((uint32_t*)hb)[i] = 0u;
    float xv = 0.f;
    if (xwriter) xv = xptr[(size_t)(r0 + mfull)*NSTEPS + (NSTEPS - 1)];  // t=0 (reversed)
    __syncthreads();          // zeros done before aug write
    if (xwriter) {
        f16 hi = (f16)xv;
        f16 lo = (f16)(xv - (float)hi);
        *(f16*)(hb + xbase + xf*2)          = hi;   // hi-plane k'=f
        *(f16*)(hb + xbase + xf*2 + 8)      = hi;   // hi-plane k'=4+f (dup)
        *(f16*)(hb + xbase + xf*2 + PLANE)  = lo;   // lo-plane k'=f
    }
    __syncthreads();

    // -------- recurrence: read phase | bar | write phase | bar --------
    #pragma unroll 1
    for (int t = 0; t < NSTEPS; ++t) {
        // prefetch next step's x early (latency hides under MFMA phase)
        float xnext = 0.f;
        if (xwriter && t + 1 < NSTEPS)
            xnext = xptr[(size_t)(r0 + mfull)*NSTEPS + (NSTEPS - 2 - t)];

        f32x4 acc00 = {bias0, bias0, bias0, bias0};
        f32x4 acc01 = {bias1, bias1, bias1, bias1};
        f32x4 acc10 = {bias0, bias0, bias0, bias0};
        f32x4 acc11 = {bias1, bias1, bias1, bias1};

        #pragma unroll
        for (int ks = 0; ks < NKS; ++ks) {
            const unsigned ra = (unsigned)(ks*1024) + (rba ^ (unsigned)((ks & 7) << 4));
            f16x8 a10 = *(const f16x8*)(hb + ra);                   // hi, mt0
            f16x8 a11 = *(const f16x8*)(hb + MTSZ + ra);            // hi, mt1
            f16x8 a20 = *(const f16x8*)(hb + PLANE + ra);           // lo, mt0
            f16x8 a21 = *(const f16x8*)(hb + PLANE + MTSZ + ra);    // lo, mt1
            acc00 = __builtin_amdgcn_mfma_f32_16x16x32_f16(a10, B1[0][ks], acc00, 0, 0, 0);
            acc01 = __builtin_amdgcn_mfma_f32_16x16x32_f16(a10, B1[1][ks], acc01, 0, 0, 0);
            acc10 = __builtin_amdgcn_mfma_f32_16x16x32_f16(a11, B1[0][ks], acc10, 0, 0, 0);
            acc11 = __builtin_amdgcn_mfma_f32_16x16x32_f16(a11, B1[1][ks], acc11, 0, 0, 0);
            acc00 = __builtin_amdgcn_mfma_f32_16x16x32_f16(a20, B1[0][ks], acc00, 0, 0, 0);
            acc01 = __builtin_amdgcn_mfma_f32_16x16x32_f16(a20, B1[1][ks], acc01, 0, 0, 0);
            acc10 = __builtin_amdgcn_mfma_f32_16x16x32_f16(a21, B1[0][ks], acc10, 0, 0, 0);
            acc11 = __builtin_amdgcn_mfma_f32_16x16x32_f16(a21, B1[1][ks], acc11, 0, 0, 0);
        }
        {   // augmented x k-step (ks=8; ks&7=0 -> no xor term)
            const unsigned ra = (unsigned)(NKS*1024) + rba;
            f16x8 a10 = *(const f16x8*)(hb + ra);
            f16x8 a11 = *(const f16x8*)(hb + MTSZ + ra);
            f16x8 a20 = *(const f16x8*)(hb + PLANE + ra);
            f16x8 a21 = *(const f16x8*)(hb + PLANE + MTSZ + ra);
            acc00 = __builtin_amdgcn_mfma_f32_16x16x32_f16(a10, Baug[0], acc00, 0, 0, 0);
            acc01 = __builtin_amdgcn_mfma_f32_16x16x32_f16(a10, Baug[1], acc01, 0, 0, 0);
            acc10 = __builtin_amdgcn_mfma_f32_16x16x32_f16(a11, Baug[0], acc10, 0, 0, 0);
            acc11 = __builtin_amdgcn_mfma_f32_16x16x32_f16(a11, Baug[1], acc11, 0, 0, 0);
            acc00 = __builtin_amdgcn_mfma_f32_16x16x32_f16(a20, Baug[0], acc00, 0, 0, 0);
            acc01 = __builtin_amdgcn_mfma_f32_16x16x32_f16(a20, Baug[1], acc01, 0, 0, 0);
            acc10 = __builtin_amdgcn_mfma_f32_16x16x32_f16(a21, Baug[0], acc10, 0, 0, 0);
            acc11 = __builtin_amdgcn_mfma_f32_16x16x32_f16(a21, Baug[1], acc11, 0, 0, 0);
        }

        __syncthreads();   // all reads of h(t)/aug(t) complete

        // aug(t+1)
        if (xwriter && t + 1 < NSTEPS) {
            f16 hi = (f16)xnext;
            f16 lo = (f16)(xnext - (float)hi);
            *(f16*)(hb + xbase + xf*2)          = hi;
            *(f16*)(hb + xbase + xf*2 + 8)      = hi;
            *(f16*)(hb + xbase + xf*2 + PLANE)  = lo;
        }
        // h(t+1): relu, split hi/lo, store
        #pragma unroll
        for (int r = 0; r < 4; ++r) {
            float v;
            f16 hi, lo;
            v = acc00[r]; v = v > 0.f ? v : 0.f;
            hi = (f16)v; lo = (f16)(v - (float)hi);
            *(f16*)(hb + waddr[0][r])                 = hi;
            *(f16*)(hb + waddr[0][r] + PLANE)         = lo;
            v = acc01[r]; v = v > 0.f ? v : 0.f;
            hi = (f16)v; lo = (f16)(v - (float)hi);
            *(f16*)(hb + waddr[1][r])                 = hi;
            *(f16*)(hb + waddr[1][r] + PLANE)         = lo;
            v = acc10[r]; v = v > 0.f ? v : 0.f;
            hi = (f16)v; lo = (f16)(v - (float)hi);
            *(f16*)(hb + waddr[0][r] + MTSZ)          = hi;
            *(f16*)(hb + waddr[0][r] + MTSZ + PLANE)  = lo;
            v = acc11[r]; v = v > 0.f ? v : 0.f;
            hi = (f16)v; lo = (f16)(v - (float)hi);
            *(f16*)(hb + waddr[1][r] + MTSZ)          = hi;
            *(f16*)(hb + waddr[1][r] + MTSZ + PLANE)  = lo;
        }
        __syncthreads();   // h(t+1)/aug(t+1) visible
    }

    // -------- final dense: out = relu(h @ Wd + b_d), reuse B1 regs --------
    #pragma unroll
    for (int nt = 0; nt < 2; ++nt) {
        const int n = n0 + nt*16 + ln16;
        #pragma unroll
        for (int ks = 0; ks < NKS; ++ks) {
            const int k0 = ks*32 + kgl*8;
            f16x8 b;
            #pragma unroll
            for (int i = 0; i < 8; ++i)
                b[i] = (f16)Wd[(size_t)(k0 + i)*CDIM + n];
            B1[nt][ks] = b;
        }
    }
    {
        const float bd0 = bd[n0 + ln16];
        const float bd1 = bd[n0 + 16 + ln16];
        f32x4 acc00 = {bd0, bd0, bd0, bd0};
        f32x4 acc01 = {bd1, bd1, bd1, bd1};
        f32x4 acc10 = {bd0, bd0, bd0, bd0};
        f32x4 acc11 = {bd1, bd1, bd1, bd1};
        #pragma unroll
        for (int ks = 0; ks < NKS; ++ks) {
            const unsigned ra = (unsigned)(ks*1024) + (rba ^ (unsigned)((ks & 7) << 4));
            f16x8 a10 = *(const f16x8*)(hb + ra);
            f16x8 a11 = *(const f16x8*)(hb + MTSZ + ra);
            f16x8 a20 = *(const f16x8*)(hb + PLANE + ra);
            f16x8 a21 = *(const f16x8*)(hb + PLANE + MTSZ + ra);
            acc00 = __builtin_amdgcn_mfma_f32_16x16x32_f16(a10, B1[0][ks], acc00, 0, 0, 0);
            acc01 = __builtin_amdgcn_mfma_f32_16x16x32_f16(a10, B1[1][ks], acc01, 0, 0, 0);
            acc10 = __builtin_amdgcn_mfma_f32_16x16x32_f16(a11, B1[0][ks], acc10, 0, 0, 0);
            acc11 = __builtin_amdgcn_mfma_f32_16x16x32_f16(a11, B1[1][ks], acc11, 0, 0, 0);
            acc00 = __builtin_amdgcn_mfma_f32_16x16x32_f16(a20, B1[0][ks], acc00, 0, 0, 0);
            acc01 = __builtin_amdgcn_mfma_f32_16x16x32_f16(a20, B1[1][ks], acc01, 0, 0, 0);
            acc10 = __builtin_amdgcn_mfma_f32_16x16x32_f16(a21, B1[0][ks], acc10, 0, 0, 0);
            acc11 = __builtin_amdgcn_mfma_f32_16x16x32_f16(a21, B1[1][ks], acc11, 0, 0, 0);
        }
        #pragma unroll
        for (int r = 0; r < 4; ++r) {
            const int mr = kgl*4 + r;
            float v;
            v = acc00[r]; out[(size_t)(r0 + mr)*CDIM      + (n0 + ln16)]      = v > 0.f ? v : 0.f;
            v = acc01[r]; out[(size_t)(r0 + mr)*CDIM      + (n0 + 16 + ln16)] = v > 0.f ? v : 0.f;
            v = acc10[r]; out[(size_t)(r0 + 16 + mr)*CDIM + (n0 + ln16)]      = v > 0.f ? v : 0.f;
            v = acc11[r]; out[(size_t)(r0 + 16 + mr)*CDIM + (n0 + 16 + ln16)] = v > 0.f ? v : 0.f;
        }
    }
}

extern "C" void kernel_launch(void* const* d_in, const int* in_sizes, int n_in,
                              void* d_out, int out_size, void* d_ws, size_t ws_size,
                              hipStream_t stream)
{
    (void)in_sizes; (void)n_in; (void)out_size; (void)d_ws; (void)ws_size;
    const float* x0 = (const float*)d_in[0];
    const float* x1 = (const float*)d_in[1];
    const float* x2 = (const float*)d_in[2];
    const float* x3 = (const float*)d_in[3];
    const float* Wx = (const float*)d_in[4];
    const float* Wh = (const float*)d_in[5];
    const float* br = (const float*)d_in[6];
    const float* Wd = (const float*)d_in[7];
    const float* bd = (const float*)d_in[8];
    float* out = (float*)d_out;

    rnn_fused<<<dim3(8192 / ROWS), dim3(512), 0, stream>>>(
        x0, x1, x2, x3, Wx, Wh, br, Wd, bd, out);
}